// Round 1
// 489.696 us; speedup vs baseline: 1.1045x; 1.1045x over previous
//
#include <hip/hip_runtime.h>
#include <hip/hip_bf16.h>
#include <stdint.h>

// EfficientAttention: B=16, C=512, HW=4096, HEADS=8, hk=hv=64
// N = B*HW = 65536.

typedef __attribute__((ext_vector_type(8))) short bf16x8;
typedef __attribute__((ext_vector_type(8))) unsigned short u16x8;
typedef __attribute__((ext_vector_type(4))) unsigned short u16x4;
typedef __attribute__((ext_vector_type(4))) float f32x4;

__device__ __forceinline__ float bf2f(unsigned short u) {
  union { unsigned int i; float f; } v; v.i = ((unsigned int)u) << 16; return v.f;
}
__device__ __forceinline__ unsigned short f2bf(float f) {
  union { float f; unsigned int i; } v; v.f = f;
  unsigned int u = v.i;
  return (unsigned short)((u + 0x7FFFu + ((u >> 16) & 1u)) >> 16);
}
__device__ __forceinline__ void gl_lds16(const void* g, void* l) {
  __builtin_amdgcn_global_load_lds((const __attribute__((address_space(1))) void*)g,
                                   (__attribute__((address_space(3))) void*)l, 16, 0, 0);
}

// ---------------- K0: pack Wk|Wq|Wv (stacked) to bf16 -----------------------
__global__ void k0_pack_w(const float* __restrict__ Wk, const float* __restrict__ Wq,
                          const float* __restrict__ Wv, unsigned short* __restrict__ Wkqv) {
  int idx = blockIdx.x * 256 + threadIdx.x;   // < 1536*512
  int o = idx >> 9, c = idx & 511;
  float v;
  if (o < 512) v = Wk[o * 512 + c];
  else if (o < 1024) v = Wq[(o - 512) * 512 + c];
  else v = Wv[(o - 1024) * 512 + c];
  Wkqv[idx] = f2bf(v);
}

// ---------------- K1: x[b][c][l] fp32 -> XbT[b*4096+l][c] bf16 (transpose) --
__global__ void k1_transpose_x(const float* __restrict__ x, unsigned short* __restrict__ XbT) {
  __shared__ unsigned short ts[64][68];
  int l0 = blockIdx.x * 64, c0 = blockIdx.y * 64, b = blockIdx.z;
  int t = threadIdx.x;
  const float* xb = x + (size_t)b * (512 * 4096);
#pragma unroll
  for (int i = 0; i < 4; i++) {
    int f = i * 256 + t;
    int cl = f >> 4, l4 = (f & 15) * 4;
    const float4 v = *(const float4*)(xb + (size_t)(c0 + cl) * 4096 + l0 + l4);
    ts[cl][l4]     = f2bf(v.x);
    ts[cl][l4 + 1] = f2bf(v.y);
    ts[cl][l4 + 2] = f2bf(v.z);
    ts[cl][l4 + 3] = f2bf(v.w);
  }
  __syncthreads();
#pragma unroll
  for (int i = 0; i < 4; i++) {
    int wv = i * 256 + t;
    int ll = wv >> 4, c4 = (wv & 15) * 4;
    u16x4 o;
    o.x = ts[c4][ll]; o.y = ts[c4 + 1][ll]; o.z = ts[c4 + 2][ll]; o.w = ts[c4 + 3][ll];
    *(u16x4*)(XbT + (size_t)(b * 4096 + l0 + ll) * 512 + c0 + c4) = o;
  }
}

// ---------------- gemm256: 256x256 tile, BK=64, 8-phase counted-vmcnt -------
// 8 waves (2M x 4N), per-wave 128x64 output. LDS 128 KiB: 2 dbuf x (A 32K + B 32K).
// LDS rows are 128 B (64 bf16); 16B-chunk c of row r holds global seg c^(r&7)
// (pre-swizzled global source, linear global_load_lds dest, swizzled ds_read)
// -> fragment ds_read_b128 is bank-conflict-free.
// Schedule per K-tile (4 phases): phase q loads A-frags mf=2q,2q+1 (+ all 8
// B-frags at q0), stages one half-tile, barrier, setprio(1)+16 MFMA, lgkm(0),
// [vmcnt(4) at q3], barrier. Staging: A(kt+1) at q0/q1, B(kt+2) at q2/q3.
// EPI=0: KQV epilogue (K/V bias store; Q in-wave 64-ch softmax -> QT).
// EPI=1: out = acc + br, fp32.
#define PHASE(bb_, q_, STAGE_STMT, TAIL_STMT)                                   \
  {                                                                             \
    const int ar_ = wm * 128 + (q_) * 32 + col;                                 \
    bf16x8 a00 = LDF((bb_), ar_, quad);                                         \
    bf16x8 a01 = LDF((bb_), ar_, 4 + quad);                                     \
    bf16x8 a10 = LDF((bb_), ar_ + 16, quad);                                    \
    bf16x8 a11 = LDF((bb_), ar_ + 16, 4 + quad);                                \
    if ((q_) == 0) {                                                            \
      _Pragma("unroll") for (int nf = 0; nf < 4; ++nf) {                        \
        bfr[nf][0] = LDF((bb_) + 16384, wn * 64 + nf * 16 + col, quad);         \
        bfr[nf][1] = LDF((bb_) + 16384, wn * 64 + nf * 16 + col, 4 + quad);     \
      }                                                                         \
    }                                                                           \
    STAGE_STMT;                                                                 \
    __builtin_amdgcn_s_barrier();                                               \
    __builtin_amdgcn_s_setprio(1);                                              \
    _Pragma("unroll") for (int nf = 0; nf < 4; ++nf) {                          \
      acc[(q_)*2][nf]   = __builtin_amdgcn_mfma_f32_16x16x32_bf16(a00, bfr[nf][0], acc[(q_)*2][nf], 0, 0, 0);   \
      acc[(q_)*2+1][nf] = __builtin_amdgcn_mfma_f32_16x16x32_bf16(a10, bfr[nf][0], acc[(q_)*2+1][nf], 0, 0, 0); \
      acc[(q_)*2][nf]   = __builtin_amdgcn_mfma_f32_16x16x32_bf16(a01, bfr[nf][1], acc[(q_)*2][nf], 0, 0, 0);   \
      acc[(q_)*2+1][nf] = __builtin_amdgcn_mfma_f32_16x16x32_bf16(a11, bfr[nf][1], acc[(q_)*2+1][nf], 0, 0, 0); \
    }                                                                           \
    __builtin_amdgcn_s_setprio(0);                                              \
    asm volatile("s_waitcnt lgkmcnt(0)" ::: "memory");                          \
    TAIL_STMT;                                                                  \
    __builtin_amdgcn_s_barrier();                                               \
  }

template <int EPI>
__global__ void __launch_bounds__(512, 2) gemm256(
    const unsigned short* __restrict__ Aall, const unsigned short* __restrict__ Ball,
    const float* __restrict__ bias0, const float* __restrict__ bias1,
    const float* __restrict__ bias2, unsigned short* __restrict__ outU,
    float* __restrict__ outF) {
  __shared__ unsigned short smem[65536];  // 128 KiB
  const int t = threadIdx.x;
  const int lane = t & 63, w = t >> 6;
  const int wm = w >> 2, wn = w & 3;
  const int col = lane & 15, quad = lane >> 4;
  const int r8 = lane >> 3, sg = lane & 7;
  const int swz = sg ^ r8;  // pre-swizzled global seg for linear LDS dest

  const int g = blockIdx.x;
  const int xcd = g & 7, j = g >> 3;
  int mi, ni;
  if (EPI == 0) { mi = j % 6; ni = (j / 6) * 8 + xcd; }
  else          { mi = j & 1; ni = (j >> 1) * 8 + xcd; }
  const int m0 = mi * 256, n0 = ni * 256;

  const unsigned short* A = (EPI == 0)
      ? Aall + (size_t)m0 * 512
      : Aall + (size_t)(n0 >> 12) * 262144 + (size_t)m0 * 512;
  const unsigned short* B = Ball + (size_t)n0 * 512;

  // stage one 128-row half-tile (16 KB): 2 x global_load_lds(16B) per thread
  auto STG = [&](const unsigned short* gbase, int ldsOff) {
    gl_lds16(gbase + (size_t)(w * 8 + r8) * 512 + swz * 8,
             (char*)smem + ((size_t)ldsOff + (size_t)(w * 8) * 64) * 2);
    gl_lds16(gbase + (size_t)(64 + w * 8 + r8) * 512 + swz * 8,
             (char*)smem + ((size_t)ldsOff + (size_t)(64 + w * 8) * 64) * 2);
  };
  // swizzled fragment read (ushort offsets; row stride 64 ushorts)
  auto LDF = [&](int baseOff, int row, int cb) -> bf16x8 {
    int ch = cb ^ (row & 7);
    return *(const bf16x8*)(smem + baseOff + row * 64 + ch * 8);
  };

  f32x4 acc[8][4];
  bf16x8 bfr[4][2];
#pragma unroll
  for (int i = 0; i < 8; ++i)
#pragma unroll
    for (int jj = 0; jj < 4; ++jj) acc[i][jj] = (f32x4){0.f, 0.f, 0.f, 0.f};

  // prologue: B(0)h0,h1; A(0)h0,h1; B(1)h0,h1  (12 loads in flight)
  STG(B, 16384);
  STG(B + (size_t)128 * 512, 16384 + 8192);
  STG(A, 0);
  STG(A + (size_t)128 * 512, 8192);
  STG(B + 64, 32768 + 16384);
  STG(B + (size_t)128 * 512 + 64, 32768 + 16384 + 8192);
  asm volatile("s_waitcnt vmcnt(4)" ::: "memory");  // B(0),A(0) landed
  __builtin_amdgcn_s_barrier();

  for (int kt = 0; kt < 6; ++kt) {
    const int bb = (kt & 1) * 32768;
    const int ob = bb ^ 32768;
    const unsigned short* An = A + (kt + 1) * 64;
    const unsigned short* Bn = B + (kt + 2) * 64;
    PHASE(bb, 0, STG(An, ob), (void)0);
    PHASE(bb, 1, STG(An + (size_t)128 * 512, ob + 8192), (void)0);
    PHASE(bb, 2, STG(Bn, bb + 16384), (void)0);
    PHASE(bb, 3, STG(Bn + (size_t)128 * 512, bb + 16384 + 8192),
          asm volatile("s_waitcnt vmcnt(4)" ::: "memory"));
  }
  {  // kt = 6: no B(8); drain everything before last tile
    const unsigned short* An = A + 7 * 64;
    PHASE(0, 0, STG(An, 32768), (void)0);
    PHASE(0, 1, STG(An + (size_t)128 * 512, 32768 + 8192), (void)0);
    PHASE(0, 2, (void)0, (void)0);
    PHASE(0, 3, (void)0, asm volatile("s_waitcnt vmcnt(0)" ::: "memory"));
  }
  {  // kt = 7: no staging
    PHASE(32768, 0, (void)0, (void)0);
    PHASE(32768, 1, (void)0, (void)0);
    PHASE(32768, 2, (void)0, (void)0);
    PHASE(32768, 3, (void)0, (void)0);
  }

  if (EPI == 1) {
    const int bIdx = n0 >> 12;
    const int l0 = (n0 & 4095) + wn * 64 + col;
    float* obp = outF + (size_t)bIdx * 2097152;
#pragma unroll
    for (int mf = 0; mf < 8; ++mf) {
      const int row0 = m0 + wm * 128 + mf * 16 + quad * 4;
#pragma unroll
      for (int r = 0; r < 4; ++r) {
        const float bi = bias0[row0 + r];
        float* op = obp + (size_t)(row0 + r) * 4096 + l0;
#pragma unroll
        for (int nf = 0; nf < 4; ++nf) op[nf * 16] = acc[mf][nf][r] + bi;
      }
    }
    return;
  }
  // ---- EPI 0: KQV epilogues
  if (m0 < 512 || m0 >= 1024) {
    const float* bb_ = (m0 < 512) ? bias0 : bias2;
    const int boff = (m0 < 512) ? 0 : 1024;
#pragma unroll
    for (int mf = 0; mf < 8; ++mf) {
      const int row0 = m0 + wm * 128 + mf * 16 + quad * 4;
#pragma unroll
      for (int r = 0; r < 4; ++r) {
        const float bi = bb_[row0 + r - boff];
        unsigned short* op = outU + (size_t)(row0 + r) * 65536 + n0 + wn * 64 + col;
#pragma unroll
        for (int nf = 0; nf < 4; ++nf) op[nf * 16] = f2bf(acc[mf][nf][r] + bi);
      }
    }
  } else {
    // Q rows: in-wave softmax over the head's 64 channels per spatial column
    unsigned short* QT = outU + (size_t)512 * 65536;
    const int cq0 = (m0 - 512) + wm * 128;
#pragma unroll
    for (int mf = 0; mf < 8; ++mf) {
      const int row0 = cq0 + mf * 16 + quad * 4;
#pragma unroll
      for (int r = 0; r < 4; ++r) {
        const float bi = bias1[row0 + r];
#pragma unroll
        for (int nf = 0; nf < 4; ++nf) acc[mf][nf][r] += bi;
      }
    }
#pragma unroll
    for (int h2 = 0; h2 < 2; ++h2)
#pragma unroll
      for (int nf = 0; nf < 4; ++nf) {
        float mx = -1e30f;
#pragma unroll
        for (int mf2 = 0; mf2 < 4; ++mf2)
#pragma unroll
          for (int r = 0; r < 4; ++r) mx = fmaxf(mx, acc[h2 * 4 + mf2][nf][r]);
        mx = fmaxf(mx, __shfl_xor(mx, 16));
        mx = fmaxf(mx, __shfl_xor(mx, 32));
        float s = 0.f;
#pragma unroll
        for (int mf2 = 0; mf2 < 4; ++mf2)
#pragma unroll
          for (int r = 0; r < 4; ++r) s += __expf(acc[h2 * 4 + mf2][nf][r] - mx);
        s += __shfl_xor(s, 16);
        s += __shfl_xor(s, 32);
        const float inv = 1.0f / s;
        const int n = n0 + wn * 64 + nf * 16 + col;
#pragma unroll
        for (int mf2 = 0; mf2 < 4; ++mf2) {
          u16x4 o;
#pragma unroll
          for (int r = 0; r < 4; ++r)
            o[r] = f2bf(__expf(acc[h2 * 4 + mf2][nf][r] - mx) * inv);
          *(u16x4*)(QT + (size_t)n * 512 + cq0 + h2 * 64 + mf2 * 16 + quad * 4) = o;
        }
      }
  }
}

// ---------------- K5: online-flash ctx partials per l-split -----------------
__global__ void __launch_bounds__(256) k5_ctx(const unsigned short* __restrict__ KQV,
                                              float* __restrict__ ctxp,
                                              float2* __restrict__ Msp) {
  __shared__ unsigned short Ks[64 * 32];
  __shared__ unsigned short Vs[64 * 32];
  __shared__ float red[64 * 4];
  int t = threadIdx.x;
  int lane = t & 63, w = t >> 6;
  int col = lane & 15, quad = lane >> 4;
  int s = blockIdx.x & 7;
  int h = (blockIdx.x >> 3) & 7;
  int b = blockIdx.x >> 6;
  int row = t >> 2, seg = t & 3;
  const unsigned short* Kbase = KQV + (size_t)(h * 64) * 65536 + b * 4096 + s * 512;
  const unsigned short* Vbase = KQV + (size_t)(1024 + h * 64) * 65536 + b * 4096 + s * 512;
  const unsigned short* krow = Kbase + (size_t)row * 65536;

  float mx = -1e30f;
#pragma unroll
  for (int kt = 0; kt < 16; kt++) {
    u16x8 kv = *(const u16x8*)(krow + kt * 32 + seg * 8);
#pragma unroll
    for (int jj = 0; jj < 8; jj++) mx = fmaxf(mx, bf2f(kv[jj]));
  }
  red[row * 4 + seg] = mx;
  __syncthreads();
  float m_row = fmaxf(fmaxf(red[row * 4], red[row * 4 + 1]),
                      fmaxf(red[row * 4 + 2], red[row * 4 + 3]));

  float sexp = 0.f;
  f32x4 zero = {0.f, 0.f, 0.f, 0.f};
  f32x4 acc[4];
#pragma unroll
  for (int i = 0; i < 4; i++) acc[i] = zero;
  for (int kt = 0; kt < 16; kt++) {
    int l0 = kt * 32;
    u16x8 kv = *(const u16x8*)(krow + l0 + seg * 8);
    u16x8 ke;
#pragma unroll
    for (int jj = 0; jj < 8; jj++) {
      float e = __expf(bf2f(kv[jj]) - m_row);
      sexp += e;
      ke[jj] = f2bf(e);
    }
    __syncthreads();
    *(u16x8*)(Ks + t * 8) = ke;
    gl_lds16(Vbase + (size_t)row * 65536 + l0 + seg * 8, (char*)Vs + (t & ~63) * 16);
    __syncthreads();
    bf16x8 a = *(const bf16x8*)(Ks + (w * 16 + col) * 32 + quad * 8);
#pragma unroll
    for (int nt = 0; nt < 4; nt++) {
      bf16x8 vb = *(const bf16x8*)(Vs + (nt * 16 + col) * 32 + quad * 8);
      acc[nt] = __builtin_amdgcn_mfma_f32_16x16x32_bf16(a, vb, acc[nt], 0, 0, 0);
    }
  }
  red[row * 4 + seg] = sexp;
  float* cb = ctxp + (((size_t)s * 16 + b) * 8 + h) * 4096;
#pragma unroll
  for (int nt = 0; nt < 4; nt++)
#pragma unroll
    for (int r = 0; r < 4; r++)
      cb[(w * 16 + quad * 4 + r) * 64 + nt * 16 + col] = acc[nt][r];
  __syncthreads();
  if (seg == 0) {
    float s_row = red[row * 4] + red[row * 4 + 1] + red[row * 4 + 2] + red[row * 4 + 3];
    Msp[((size_t)(b * 8 + h) * 64 + row) * 8 + s] = make_float2(m_row, s_row);
  }
}

// ---------------- K6: fused rescale-combine + Wr fold -> Mb (bf16) ----------
__global__ void __launch_bounds__(256) k6_fold(const float* __restrict__ Wr,
                                               const float* __restrict__ ctxp,
                                               const float2* __restrict__ Msp,
                                               unsigned short* __restrict__ Mb) {
  __shared__ float gf[8][64];
  __shared__ float ctxs[64][64];
  int oc = blockIdx.x, h = blockIdx.y, b = blockIdx.z;
  int t = threadIdx.x;
  if (t < 64) {
    int kc = t;
    const float2* mp = Msp + ((size_t)(b * 8 + h) * 64 + kc) * 8;
    float2 v[8];
    float m = -1e30f;
#pragma unroll
    for (int s = 0; s < 8; s++) { v[s] = mp[s]; m = fmaxf(m, v[s].x); }
    float f[8], ssum = 0.f;
#pragma unroll
    for (int s = 0; s < 8; s++) { f[s] = __expf(v[s].x - m); ssum += v[s].y * f[s]; }
    float inv = 1.0f / ssum;
#pragma unroll
    for (int s = 0; s < 8; s++) gf[s][kc] = f[s] * inv;
  }
  __syncthreads();
#pragma unroll
  for (int i = 0; i < 16; i++) {
    int p = i * 256 + t;
    int kc = p >> 6;
    float a = 0.f;
#pragma unroll
    for (int s = 0; s < 8; s++)
      a += ctxp[(((size_t)s * 16 + b) * 8 + h) * 4096 + p] * gf[s][kc];
    ((float*)ctxs)[p] = a;
  }
  __syncthreads();
  int o = oc * 128 + (t >> 1);
  int kh = (t & 1) * 32;
  const float* wrp = Wr + (size_t)o * 512 + h * 64;
  float acc2[32];
#pragma unroll
  for (int kc = 0; kc < 32; kc++) acc2[kc] = 0.f;
#pragma unroll
  for (int v4 = 0; v4 < 16; v4++) {
    float4 wv = *(const float4*)(wrp + v4 * 4);
#pragma unroll
    for (int kc = 0; kc < 32; kc++) {
      const float4 c4 = *(const float4*)(&ctxs[kh + kc][v4 * 4]);
      acc2[kc] += wv.x * c4.x + wv.y * c4.y + wv.z * c4.z + wv.w * c4.w;
    }
  }
  unsigned short* mp = Mb + (size_t)b * 262144 + (size_t)o * 512 + h * 64 + kh;
#pragma unroll
  for (int jj = 0; jj < 4; jj++) {
    u16x8 ov;
#pragma unroll
    for (int e = 0; e < 8; e++) ov[e] = f2bf(acc2[jj * 8 + e]);
    *(u16x8*)(mp + jj * 8) = ov;
  }
}

extern "C" void kernel_launch(void* const* d_in, const int* in_sizes, int n_in,
                              void* d_out, int out_size, void* d_ws, size_t ws_size,
                              hipStream_t stream) {
  const float* x  = (const float*)d_in[0];
  const float* Wk = (const float*)d_in[1];
  const float* bk = (const float*)d_in[2];
  const float* Wq = (const float*)d_in[3];
  const float* bq = (const float*)d_in[4];
  const float* Wv = (const float*)d_in[5];
  const float* bv = (const float*)d_in[6];
  const float* Wr = (const float*)d_in[7];
  const float* br = (const float*)d_in[8];
  float* out = (float*)d_out;

  char* ws = (char*)d_ws;
  const size_t MiB = 1024 * 1024;
  unsigned short* XbT  = (unsigned short*)ws;
  unsigned short* Wkqv = (unsigned short*)(ws + 64 * MiB);
  unsigned short* KQV  = (unsigned short*)(ws + 64 * MiB + 1536 * 1024);
  unsigned short* QT   = KQV + (size_t)512 * 65536;
  float2*         Msp  = (float2*)ws;
  float*          ctxp = (float*)(ws + 1 * MiB);
  unsigned short* Mb   = (unsigned short*)(ws + 20 * MiB);

  k0_pack_w<<<3072, 256, 0, stream>>>(Wk, Wq, Wv, Wkqv);
  k1_transpose_x<<<dim3(64, 8, 16), 256, 0, stream>>>(x, XbT);
  gemm256<0><<<1536, 512, 0, stream>>>(Wkqv, XbT, bk, bq, bv, KQV, nullptr);
  k5_ctx<<<1024, 256, 0, stream>>>(KQV, ctxp, Msp);
  k6_fold<<<dim3(4, 8, 16), 256, 0, stream>>>(Wr, ctxp, Msp, Mb);
  gemm256<1><<<512, 512, 0, stream>>>(Mb, QT, br, nullptr, nullptr, nullptr, out);
}